// Round 1
// baseline (974.833 us; speedup 1.0000x reference)
//
#include <hip/hip_runtime.h>
#include <stdint.h>

#define TB 256
#define BM 128
#define BN 128
#define BK 32
#define LSTR 40   // LDS row stride in bf16 elems: 80 B = 20 banks; 16B-aligned rows

typedef __attribute__((ext_vector_type(8))) short bf16x8;
typedef __attribute__((ext_vector_type(4))) float f32x4;
typedef __attribute__((ext_vector_type(4))) unsigned short ush4;

// fp32 -> (hi, lo) bf16 pair, both RNE. a ~= hi + lo to ~2^-17 rel.
__device__ __forceinline__ void split2(float x, unsigned short& h, unsigned short& l) {
  uint32_t u = __float_as_uint(x);
  uint32_t rh = u + 0x7FFFu + ((u >> 16) & 1u);
  unsigned short hi = (unsigned short)(rh >> 16);
  float hf = __uint_as_float((uint32_t)hi << 16);
  float res = x - hf;
  uint32_t v = __float_as_uint(res);
  uint32_t rl = v + 0x7FFFu + ((v >> 16) & 1u);
  h = hi;
  l = (unsigned short)(rl >> 16);
}

// valid_mask dtype probe: uint8 bools -> byte-sum ~ nbytes/2; int32 0/1 -> ~ nbytes/8.
__global__ void mask_probe_kernel(const uint8_t* __restrict__ m, int nbytes, int* __restrict__ flag) {
  __shared__ int s[TB];
  int t = threadIdx.x;
  int acc = 0;
  for (int i = t; i < nbytes; i += TB) acc += m[i];
  s[t] = acc;
  __syncthreads();
  for (int w = TB / 2; w > 0; w >>= 1) {
    if (t < w) s[t] += s[t + w];
    __syncthreads();
  }
  if (t == 0) *flag = (s[0] * 10 >= nbytes * 3) ? 1 : 0;  // 1 => uint8 layout
}

// C[M,N] = act(A[M,K] @ B[K,N] + bias), optional row mask. M == gridDim.y*BM.
// Split-bf16: 3 MFMA per fragment pair (hi*hi + hi*lo + lo*hi).
template<bool RELU, bool MASKED, bool BCHK>
__global__ __launch_bounds__(TB, 1)
void mlp_gemm(const float* __restrict__ A, const float* __restrict__ Bw,
              const float* __restrict__ bias, const void* __restrict__ maskp,
              const int* __restrict__ mflag, float* __restrict__ C,
              int N, int K)
{
  // [buf][hi/lo][rows*LSTR] ; A rows = M-tile rows, B rows = N-tile cols (transposed)
  __shared__ unsigned short sA[2][2][BM * LSTR];
  __shared__ unsigned short sB[2][2][BN * LSTR];

  const int tid = threadIdx.x;

  // XCD-grouped decode: XCD (= L%8 round-robin) owns a contiguous bm chunk, all bn.
  int L = blockIdx.y * gridDim.x + blockIdx.x;
  int gy8 = gridDim.y >> 3;                 // bm rows per XCD
  int bm = (L & 7) * gy8 + ((L >> 3) % gy8);
  int bn = (L >> 3) / gy8;

  // A staging: thread -> (row, 16-col half); 4 float4 per K-step
  const int ar  = tid >> 1;
  const int ac0 = (tid & 1) * 16;
  const int sa  = (ar >> 1) & 3;            // 16B-block XOR swizzle key
  const float* Ag = A + (size_t)(bm * BM + ar) * K + ac0;

  // B staging: thread -> (k-row, col quad); 4 float4 per K-step, written transposed
  const int bk  = tid >> 3;
  const int bc0 = (tid & 7) * 4;
  const int kbb = bk >> 3;
  const int ko  = bk & 7;
  const float* Bg = Bw + (size_t)bk * N + bn * BN + bc0;
  const int bn0 = bn * BN + bc0;

  const int lane = tid & 63;
  const int wid  = tid >> 6;
  const int wr = wid >> 1, wc = wid & 1;    // 2x2 wave grid, 64x64 per wave
  const int fr = lane & 15, g = lane >> 4;

  f32x4 acc[4][4];
#pragma unroll
  for (int m = 0; m < 4; ++m)
#pragma unroll
    for (int n = 0; n < 4; ++n) {
      f32x4 z = {0.f, 0.f, 0.f, 0.f};
      acc[m][n] = z;
    }

  // Fragment LDS offsets (elems), swizzle folded in.
  int aoff[4], boff[4];
#pragma unroll
  for (int m = 0; m < 4; ++m) {
    int r = wr * 64 + m * 16 + fr;
    aoff[m] = r * LSTR + ((g ^ ((r >> 1) & 3)) << 3);
  }
#pragma unroll
  for (int n = 0; n < 4; ++n) {
    int r = wc * 64 + n * 16 + fr;
    boff[n] = r * LSTR + ((g ^ ((r >> 1) & 3)) << 3);
  }

  float4 arg_[4], brg_[4];

  auto stage_load = [&](int kt) {
    const float4* ap = (const float4*)(Ag + (size_t)kt * BK);
#pragma unroll
    for (int q = 0; q < 4; ++q) arg_[q] = ap[q];
    const float4* bp = (const float4*)(Bg + (size_t)kt * BK * N);
#pragma unroll
    for (int q = 0; q < 4; ++q) {
      if (!BCHK || (bn0 + 32 * q) < N) brg_[q] = bp[8 * q];
      else brg_[q] = make_float4(0.f, 0.f, 0.f, 0.f);
    }
  };

  auto stage_write = [&](int buf) {
#pragma unroll
    for (int q = 0; q < 4; ++q) {           // A: b64 writes, hi & lo planes
      int c = ac0 + 4 * q;
      int cc = (((c >> 3) ^ sa) << 3) + (c & 7);
      unsigned short h0, h1, h2, h3, l0, l1, l2, l3;
      split2(arg_[q].x, h0, l0);
      split2(arg_[q].y, h1, l1);
      split2(arg_[q].z, h2, l2);
      split2(arg_[q].w, h3, l3);
      ush4 h = {h0, h1, h2, h3};
      ush4 l = {l0, l1, l2, l3};
      *(ush4*)&sA[buf][0][ar * LSTR + cc] = h;
      *(ush4*)&sA[buf][1][ar * LSTR + cc] = l;
    }
#pragma unroll
    for (int q = 0; q < 4; ++q) {           // B: transposed b16 scatter
      float bv[4] = {brg_[q].x, brg_[q].y, brg_[q].z, brg_[q].w};
#pragma unroll
      for (int i = 0; i < 4; ++i) {
        int c = bc0 + 32 * q + i;           // n within tile = LDS row
        int cc = ((kbb ^ ((c >> 1) & 3)) << 3) + ko;
        unsigned short h, l;
        split2(bv[i], h, l);
        sB[buf][0][c * LSTR + cc] = h;
        sB[buf][1][c * LSTR + cc] = l;
      }
    }
  };

  auto compute = [&](int buf) {
    bf16x8 bh[4], bl[4];
#pragma unroll
    for (int n = 0; n < 4; ++n) {
      bh[n] = *(const bf16x8*)&sB[buf][0][boff[n]];
      bl[n] = *(const bf16x8*)&sB[buf][1][boff[n]];
    }
#pragma unroll
    for (int m = 0; m < 4; ++m) {
      bf16x8 ah = *(const bf16x8*)&sA[buf][0][aoff[m]];
      bf16x8 al = *(const bf16x8*)&sA[buf][1][aoff[m]];
#pragma unroll
      for (int n = 0; n < 4; ++n) {
        acc[m][n] = __builtin_amdgcn_mfma_f32_16x16x32_bf16(ah, bh[n], acc[m][n], 0, 0, 0);
        acc[m][n] = __builtin_amdgcn_mfma_f32_16x16x32_bf16(ah, bl[n], acc[m][n], 0, 0, 0);
        acc[m][n] = __builtin_amdgcn_mfma_f32_16x16x32_bf16(al, bh[n], acc[m][n], 0, 0, 0);
      }
    }
  };

  const int nkt = K / BK;
  stage_load(0);
  stage_write(0);
  __syncthreads();
  for (int kt = 0; kt < nkt; ++kt) {
    int buf = kt & 1;
    bool more = (kt + 1) < nkt;
    if (more) stage_load(kt + 1);   // issue early: HBM latency hides under MFMA
    compute(buf);
    if (more) stage_write(buf ^ 1); // write late, into the other buffer
    __syncthreads();
  }

  // Epilogue: C/D layout col = lane&15, row = (lane>>4)*4 + reg
  const int crow0 = bm * BM + wr * 64 + g * 4;
  const int ccol0 = bn * BN + wc * 64 + fr;
  int mf = 0;
  if (MASKED) mf = *mflag;
#pragma unroll
  for (int n = 0; n < 4; ++n) {
    int col = ccol0 + n * 16;
    if (BCHK && col >= N) continue;
    float bvv = bias[col];
#pragma unroll
    for (int m = 0; m < 4; ++m) {
#pragma unroll
      for (int j = 0; j < 4; ++j) {
        int row = crow0 + m * 16 + j;
        float v = acc[m][n][j] + bvv;
        if (RELU) v = fmaxf(v, 0.f);
        if (MASKED) {
          bool ok = mf ? (((const uint8_t*)maskp)[row] != 0)
                       : (((const int*)maskp)[row] != 0);
          v = ok ? v : 0.f;
        }
        C[(size_t)row * N + col] = v;
      }
    }
  }
}

extern "C" void kernel_launch(void* const* d_in, const int* in_sizes, int n_in,
                              void* d_out, int out_size, void* d_ws, size_t ws_size,
                              hipStream_t stream) {
  const float* feat  = (const float*)d_in[0];
  const void*  vmask = d_in[1];
  // d_in[2] = features_size_pred (unused; shapes are static)
  const float* W1 = (const float*)d_in[3];
  const float* b1 = (const float*)d_in[4];
  const float* W2 = (const float*)d_in[5];
  const float* b2 = (const float*)d_in[6];
  const float* Wp = (const float*)d_in[7];
  const float* bp = (const float*)d_in[8];
  float* out = (float*)d_out;

  float* H1 = (float*)d_ws;                          // 4096x1024 f32
  float* H2 = H1 + (size_t)4096 * 1024;              // 4096x1024 f32
  int* mflag = (int*)((char*)d_ws + (size_t)2 * 4096 * 1024 * 4);

  mask_probe_kernel<<<1, TB, 0, stream>>>((const uint8_t*)vmask, 4096, mflag);

  // GEMM1: features [4096,12544] @ W1 [12544,1024] -> H1, +b1, ReLU
  mlp_gemm<true,  false, false><<<dim3(8, 32), TB, 0, stream>>>(feat, W1, b1, nullptr, mflag, H1, 1024, 12544);
  // GEMM2: H1 @ W2 [1024,1024] -> H2, +b2, ReLU
  mlp_gemm<true,  false, false><<<dim3(8, 32), TB, 0, stream>>>(H1,   W2, b2, nullptr, mflag, H2, 1024, 1024);
  // GEMM3: H2 @ Wp [1024,324] -> out, +bp, mask rows
  mlp_gemm<false, true,  true ><<<dim3(3, 32), TB, 0, stream>>>(H2,   Wp, bp, vmask,  mflag, out, 324, 1024);
}

// Round 3
// 708.382 us; speedup vs baseline: 1.3761x; 1.3761x over previous
//
#include <hip/hip_runtime.h>
#include <stdint.h>

#define TB 256

typedef unsigned short ush;
typedef __attribute__((ext_vector_type(8))) short bf16x8;
typedef __attribute__((ext_vector_type(8))) unsigned short ush8;
typedef __attribute__((ext_vector_type(4))) float f32x4;
typedef __attribute__((ext_vector_type(4))) unsigned short ush4;

// fp32 -> (hi, lo) bf16 pair, both RNE. a ~= hi + lo to ~2^-17 rel.
__device__ __forceinline__ void split2(float x, ush& h, ush& l) {
  uint32_t u = __float_as_uint(x);
  uint32_t rh = u + 0x7FFFu + ((u >> 16) & 1u);
  ush hi = (ush)(rh >> 16);
  float hf = __uint_as_float((uint32_t)hi << 16);
  float res = x - hf;
  uint32_t v = __float_as_uint(res);
  uint32_t rl = v + 0x7FFFu + ((v >> 16) & 1u);
  h = hi;
  l = (ush)(rl >> 16);
}

__device__ __forceinline__ void gll16(const void* g, void* l) {
  __builtin_amdgcn_global_load_lds((const __attribute__((address_space(1))) void*)g,
                                   (__attribute__((address_space(3))) void*)l, 16, 0, 0);
}

// valid_mask dtype probe: uint8 bools -> byte-sum ~ nbytes/2; int32 0/1 -> ~ nbytes/8.
__global__ void mask_probe_kernel(const uint8_t* __restrict__ m, int nbytes, int* __restrict__ flag) {
  __shared__ int s[TB];
  int t = threadIdx.x;
  int acc = 0;
  for (int i = t; i < nbytes; i += TB) acc += m[i];
  s[t] = acc;
  __syncthreads();
  for (int w = TB / 2; w > 0; w >>= 1) {
    if (t < w) s[t] += s[t + w];
    __syncthreads();
  }
  if (t == 0) *flag = (s[0] * 10 >= nbytes * 3) ? 1 : 0;  // 1 => uint8 layout
}

// ============================ TIER A =====================================
// Image format: per 128x32 bf16 tile, 512 slots of 8 elems (16B).
// Slot (r, b) holds logical k-block b^(r&3) of row r  (bank swizzle baked in).
// Tile index: A: bm*NKT + kt ; B(transposed): bn*NKT + kt.

// features [4096,12544] f32 -> Ah/Al images.  grid(2, 392, 32)
__global__ __launch_bounds__(TB)
void conv_A(const float* __restrict__ F, ush* __restrict__ Ah, ush* __restrict__ Al) {
  int slot = blockIdx.x * TB + threadIdx.x;  // 0..511
  int kt = blockIdx.y, bm = blockIdx.z;
  int r = slot >> 2, b = slot & 3, b0 = b ^ (r & 3);
  const float* s = F + (size_t)(bm * 128 + r) * 12544 + kt * 32 + b0 * 8;
  float4 v0 = *(const float4*)s;
  float4 v1 = *(const float4*)(s + 4);
  float vv[8] = {v0.x, v0.y, v0.z, v0.w, v1.x, v1.y, v1.z, v1.w};
  ush8 h, l;
#pragma unroll
  for (int j = 0; j < 8; ++j) { ush hh, ll; split2(vv[j], hh, ll); h[j] = hh; l[j] = ll; }
  size_t d = ((size_t)(bm * 392 + kt) * 512 + slot) * 8;
  *(ush8*)(Ah + d) = h;
  *(ush8*)(Al + d) = l;
}

// W [K, N_src] f32 -> transposed images [NBN tiles][NKT][512 slots]. grid(2, NKT, NBN)
__global__ __launch_bounds__(TB)
void conv_BT(const float* __restrict__ W, ush* __restrict__ Bh, ush* __restrict__ Bl,
             int N_src, int NKT) {
  int slot = blockIdx.x * TB + threadIdx.x;
  int kt = blockIdx.y, bn = blockIdx.z;
  int r = slot >> 2, b = slot & 3, b0 = b ^ (r & 3);
  int n = bn * 128 + r;
  int k0 = kt * 32 + b0 * 8;
  ush8 h, l;
#pragma unroll
  for (int j = 0; j < 8; ++j) {
    float v = (n < N_src) ? W[(size_t)(k0 + j) * N_src + n] : 0.f;
    ush hh, ll; split2(v, hh, ll); h[j] = hh; l[j] = ll;
  }
  size_t d = ((size_t)(bn * NKT + kt) * 512 + slot) * 8;
  *(ush8*)(Bh + d) = h;
  *(ush8*)(Bl + d) = l;
}

// Split-bf16 GEMM from images. grid(NBN, 32, 2). P partials, layout:
// P[((kz*32+bm)*NBN+bn)*16384 + wid*4096 + (m*4+n)*256 + lane*4 + j]
__global__ __launch_bounds__(TB, 2)
void gemm_sp(const ush* __restrict__ Ah, const ush* __restrict__ Al,
             const ush* __restrict__ Bh, const ush* __restrict__ Bl,
             float* __restrict__ P, int NKT) {
  __shared__ __align__(16) ush sL[2][4][4096];
  const int tid = threadIdx.x;
  const int NBN = gridDim.x;
  int nwg = NBN * 64;
  int L = (blockIdx.z * 32 + blockIdx.y) * NBN + blockIdx.x;
  int q8 = nwg >> 3;
  int wg = (L & 7) * q8 + (L >> 3);            // XCD-chunked, nwg%8==0 for all grids
  int bn = wg % NBN;
  int rem = wg / NBN;
  int bm = rem & 31, kz = rem >> 5;
  const int nkt_h = NKT >> 1;
  const int kt0 = kz * nkt_h;

  const int lane = tid & 63, wid = tid >> 6;
  const int wr = wid >> 1, wc = wid & 1;
  const int fr = lane & 15, g = lane >> 4;

  int aoff[4], boff[4];
#pragma unroll
  for (int m = 0; m < 4; ++m) {
    int r = wr * 64 + m * 16 + fr;
    aoff[m] = r * 32 + ((g ^ (r & 3)) << 3);
  }
#pragma unroll
  for (int n = 0; n < 4; ++n) {
    int r = wc * 64 + n * 16 + fr;
    boff[n] = r * 32 + ((g ^ (r & 3)) << 3);
  }

  f32x4 acc[4][4];
#pragma unroll
  for (int m = 0; m < 4; ++m)
#pragma unroll
    for (int n = 0; n < 4; ++n) { f32x4 z = {0.f, 0.f, 0.f, 0.f}; acc[m][n] = z; }

  const size_t baseA = (size_t)bm * NKT + kt0;
  const size_t baseB = (size_t)bn * NKT + kt0;
  const int t8 = tid * 8;

  auto stage = [&](int buf, int kt) {
    const ush* a_h = Ah + (baseA + kt) * 4096 + t8;
    const ush* a_l = Al + (baseA + kt) * 4096 + t8;
    const ush* b_h = Bh + (baseB + kt) * 4096 + t8;
    const ush* b_l = Bl + (baseB + kt) * 4096 + t8;
    ush* d = &sL[buf][0][0] + (tid & ~63) * 8;
    gll16(a_h, d);                gll16(a_h + 2048, d + 2048);
    gll16(a_l, d + 4096);         gll16(a_l + 2048, d + 6144);
    gll16(b_h, d + 8192);         gll16(b_h + 2048, d + 10240);
    gll16(b_l, d + 12288);        gll16(b_l + 2048, d + 14336);
  };

  auto compute = [&](int buf) {
    const ush* A0 = &sL[buf][0][0];
    const ush* A1 = &sL[buf][1][0];
    const ush* B0 = &sL[buf][2][0];
    const ush* B1 = &sL[buf][3][0];
    bf16x8 bh[4], bl[4];
#pragma unroll
    for (int n = 0; n < 4; ++n) {
      bh[n] = *(const bf16x8*)(B0 + boff[n]);
      bl[n] = *(const bf16x8*)(B1 + boff[n]);
    }
#pragma unroll
    for (int m = 0; m < 4; ++m) {
      bf16x8 ah = *(const bf16x8*)(A0 + aoff[m]);
      bf16x8 al = *(const bf16x8*)(A1 + aoff[m]);
#pragma unroll
      for (int n = 0; n < 4; ++n)
        acc[m][n] = __builtin_amdgcn_mfma_f32_16x16x32_bf16(ah, bh[n], acc[m][n], 0, 0, 0);
#pragma unroll
      for (int n = 0; n < 4; ++n)
        acc[m][n] = __builtin_amdgcn_mfma_f32_16x16x32_bf16(ah, bl[n], acc[m][n], 0, 0, 0);
#pragma unroll
      for (int n = 0; n < 4; ++n)
        acc[m][n] = __builtin_amdgcn_mfma_f32_16x16x32_bf16(al, bh[n], acc[m][n], 0, 0, 0);
    }
  };

  stage(0, 0);
  __syncthreads();
  for (int kt = 0; kt < nkt_h; ++kt) {
    int buf = kt & 1;
    if (kt + 1 < nkt_h) stage(buf ^ 1, kt + 1);
    compute(buf);
    __syncthreads();
  }

  float* Pb = P + (((size_t)kz * 32 + bm) * NBN + bn) * 16384 + wid * 4096;
#pragma unroll
  for (int m = 0; m < 4; ++m)
#pragma unroll
    for (int n = 0; n < 4; ++n)
      *(f32x4*)&Pb[(m * 4 + n) * 256 + lane * 4] = acc[m][n];
}

// P(kz=0)+P(kz=1) + bias, ReLU, split -> H images (NKT2=32). grid(NBN=8, 32)
__global__ __launch_bounds__(TB)
void combine_img(const float* __restrict__ P, const float* __restrict__ bias,
                 ush* __restrict__ Hh, ush* __restrict__ Hl) {
  __shared__ float sC[16384];
  int t = threadIdx.x;
  int bn = blockIdx.x, bm = blockIdx.y, NBN = gridDim.x;
  const float* P0 = P + ((size_t)bm * NBN + bn) * 16384;
  const float* P1 = P + ((size_t)(32 + bm) * NBN + bn) * 16384;
#pragma unroll 4
  for (int c = 0; c < 64; ++c) {
    int idx = c * 256 + t;
    float v = P0[idx] + P1[idx];
    int w = c >> 4, mn = c & 15, m = mn >> 2, n = mn & 3, ln = t >> 2, j = t & 3;
    int row = (w >> 1) * 64 + m * 16 + (ln >> 4) * 4 + j;
    int col = (w & 1) * 64 + n * 16 + (ln & 15);
    sC[row * 128 + col] = v;
  }
  __syncthreads();
#pragma unroll
  for (int i = 0; i < 8; ++i) {
    int u = i * 256 + t;
    int qq = u >> 9, s = u & 511, r = s >> 2, b = s & 3, b0 = b ^ (r & 3);
    int c0 = qq * 32 + b0 * 8;
    ush8 h, l;
#pragma unroll
    for (int j = 0; j < 8; ++j) {
      float v = fmaxf(sC[r * 128 + c0 + j] + bias[bn * 128 + c0 + j], 0.f);
      ush hh, ll; split2(v, hh, ll); h[j] = hh; l[j] = ll;
    }
    size_t d = ((size_t)(bm * 32 + bn * 4 + qq) * 512 + s) * 8;
    *(ush8*)(Hh + d) = h;
    *(ush8*)(Hl + d) = l;
  }
}

// P sum + bias, row mask, -> out f32 [4096,324]. grid(3, 32)
__global__ __launch_bounds__(TB)
void combine_out(const float* __restrict__ P, const float* __restrict__ bp,
                 const void* __restrict__ maskp, const int* __restrict__ mflag,
                 float* __restrict__ out) {
  __shared__ float sC[16384];
  int t = threadIdx.x;
  int bn = blockIdx.x, bm = blockIdx.y;
  const float* P0 = P + ((size_t)bm * 3 + bn) * 16384;
  const float* P1 = P + ((size_t)(32 + bm) * 3 + bn) * 16384;
#pragma unroll 4
  for (int c = 0; c < 64; ++c) {
    int idx = c * 256 + t;
    float v = P0[idx] + P1[idx];
    int w = c >> 4, mn = c & 15, m = mn >> 2, n = mn & 3, ln = t >> 2, j = t & 3;
    int row = (w >> 1) * 64 + m * 16 + (ln >> 4) * 4 + j;
    int col = (w & 1) * 64 + n * 16 + (ln & 15);
    sC[row * 128 + col] = v;
  }
  __syncthreads();
  int mf = *mflag;
#pragma unroll
  for (int i = 0; i < 8; ++i) {
    int u = i * 256 + t;
    int qq = u >> 9, s = u & 511, r = s >> 2, b = s & 3, b0 = b ^ (r & 3);
    int c0 = qq * 32 + b0 * 8;
    int grow = bm * 128 + r;
    bool ok = mf ? (((const uint8_t*)maskp)[grow] != 0)
                 : (((const int*)maskp)[grow] != 0);
#pragma unroll
    for (int j = 0; j < 8; ++j) {
      int col = bn * 128 + c0 + j;
      if (col < 324) {
        float v = sC[r * 128 + c0 + j] + bp[col];
        out[(size_t)grow * 324 + col] = ok ? v : 0.f;
      }
    }
  }
}

// ============================ TIER C (fallback, proven round-1) ==========
#define BM 128
#define BN 128
#define BK 32
#define LSTR 40

template<bool RELU, bool MASKED, bool BCHK>
__global__ __launch_bounds__(TB, 1)
void mlp_gemm(const float* __restrict__ A, const float* __restrict__ Bw,
              const float* __restrict__ bias, const void* __restrict__ maskp,
              const int* __restrict__ mflag, float* __restrict__ C,
              int N, int K)
{
  __shared__ ush sA[2][2][BM * LSTR];
  __shared__ ush sB[2][2][BN * LSTR];
  const int tid = threadIdx.x;
  int L = blockIdx.y * gridDim.x + blockIdx.x;
  int gy8 = gridDim.y >> 3;
  int bm = (L & 7) * gy8 + ((L >> 3) % gy8);
  int bn = (L >> 3) / gy8;
  const int ar  = tid >> 1;
  const int ac0 = (tid & 1) * 16;
  const int sa  = (ar >> 1) & 3;
  const float* Ag = A + (size_t)(bm * BM + ar) * K + ac0;
  const int bk  = tid >> 3;
  const int bc0 = (tid & 7) * 4;
  const int kbb = bk >> 3;
  const int ko  = bk & 7;
  const float* Bg = Bw + (size_t)bk * N + bn * BN + bc0;
  const int bn0 = bn * BN + bc0;
  const int lane = tid & 63;
  const int wid  = tid >> 6;
  const int wr = wid >> 1, wc = wid & 1;
  const int fr = lane & 15, g = lane >> 4;
  f32x4 acc[4][4];
#pragma unroll
  for (int m = 0; m < 4; ++m)
#pragma unroll
    for (int n = 0; n < 4; ++n) { f32x4 z = {0.f,0.f,0.f,0.f}; acc[m][n] = z; }
  int aoff[4], boff[4];
#pragma unroll
  for (int m = 0; m < 4; ++m) {
    int r = wr * 64 + m * 16 + fr;
    aoff[m] = r * LSTR + ((g ^ ((r >> 1) & 3)) << 3);
  }
#pragma unroll
  for (int n = 0; n < 4; ++n) {
    int r = wc * 64 + n * 16 + fr;
    boff[n] = r * LSTR + ((g ^ ((r >> 1) & 3)) << 3);
  }
  float4 arg_[4], brg_[4];
  auto stage_load = [&](int kt) {
    const float4* ap = (const float4*)(Ag + (size_t)kt * BK);
#pragma unroll
    for (int q = 0; q < 4; ++q) arg_[q] = ap[q];
    const float4* bp = (const float4*)(Bg + (size_t)kt * BK * N);
#pragma unroll
    for (int q = 0; q < 4; ++q) {
      if (!BCHK || (bn0 + 32 * q) < N) brg_[q] = bp[8 * q];
      else brg_[q] = make_float4(0.f, 0.f, 0.f, 0.f);
    }
  };
  auto stage_write = [&](int buf) {
#pragma unroll
    for (int q = 0; q < 4; ++q) {
      int c = ac0 + 4 * q;
      int cc = (((c >> 3) ^ sa) << 3) + (c & 7);
      ush h0,h1,h2,h3,l0,l1,l2,l3;
      split2(arg_[q].x, h0, l0); split2(arg_[q].y, h1, l1);
      split2(arg_[q].z, h2, l2); split2(arg_[q].w, h3, l3);
      ush4 h = {h0,h1,h2,h3}; ush4 l = {l0,l1,l2,l3};
      *(ush4*)&sA[buf][0][ar * LSTR + cc] = h;
      *(ush4*)&sA[buf][1][ar * LSTR + cc] = l;
    }
#pragma unroll
    for (int q = 0; q < 4; ++q) {
      float bv[4] = {brg_[q].x, brg_[q].y, brg_[q].z, brg_[q].w};
#pragma unroll
      for (int i = 0; i < 4; ++i) {
        int c = bc0 + 32 * q + i;
        int cc = ((kbb ^ ((c >> 1) & 3)) << 3) + ko;
        ush h, l; split2(bv[i], h, l);
        sB[buf][0][c * LSTR + cc] = h;
        sB[buf][1][c * LSTR + cc] = l;
      }
    }
  };
  auto compute = [&](int buf) {
    bf16x8 bh[4], bl[4];
#pragma unroll
    for (int n = 0; n < 4; ++n) {
      bh[n] = *(const bf16x8*)&sB[buf][0][boff[n]];
      bl[n] = *(const bf16x8*)&sB[buf][1][boff[n]];
    }
#pragma unroll
    for (int m = 0; m < 4; ++m) {
      bf16x8 ah = *(const bf16x8*)&sA[buf][0][aoff[m]];
      bf16x8 al = *(const bf16x8*)&sA[buf][1][aoff[m]];
#pragma unroll
      for (int n = 0; n < 4; ++n) {
        acc[m][n] = __builtin_amdgcn_mfma_f32_16x16x32_bf16(ah, bh[n], acc[m][n], 0, 0, 0);
        acc[m][n] = __builtin_amdgcn_mfma_f32_16x16x32_bf16(ah, bl[n], acc[m][n], 0, 0, 0);
        acc[m][n] = __builtin_amdgcn_mfma_f32_16x16x32_bf16(al, bh[n], acc[m][n], 0, 0, 0);
      }
    }
  };
  const int nkt = K / BK;
  stage_load(0);
  stage_write(0);
  __syncthreads();
  for (int kt = 0; kt < nkt; ++kt) {
    int buf = kt & 1;
    bool more = (kt + 1) < nkt;
    if (more) stage_load(kt + 1);
    compute(buf);
    if (more) stage_write(buf ^ 1);
    __syncthreads();
  }
  const int crow0 = bm * BM + wr * 64 + g * 4;
  const int ccol0 = bn * BN + wc * 64 + fr;
  int mf = 0;
  if (MASKED) mf = *mflag;
#pragma unroll
  for (int n = 0; n < 4; ++n) {
    int col = ccol0 + n * 16;
    if (BCHK && col >= N) continue;
    float bvv = bias[col];
#pragma unroll
    for (int m = 0; m < 4; ++m) {
#pragma unroll
      for (int j = 0; j < 4; ++j) {
        int row = crow0 + m * 16 + j;
        float v = acc[m][n][j] + bvv;
        if (RELU) v = fmaxf(v, 0.f);
        if (MASKED) {
          bool ok = mf ? (((const uint8_t*)maskp)[row] != 0)
                       : (((const int*)maskp)[row] != 0);
          v = ok ? v : 0.f;
        }
        C[(size_t)row * N + col] = v;
      }
    }
  }
}

// ============================ launcher ===================================
extern "C" void kernel_launch(void* const* d_in, const int* in_sizes, int n_in,
                              void* d_out, int out_size, void* d_ws, size_t ws_size,
                              hipStream_t stream) {
  const float* feat  = (const float*)d_in[0];
  const void*  vmask = d_in[1];
  const float* W1 = (const float*)d_in[3];
  const float* b1 = (const float*)d_in[4];
  const float* W2 = (const float*)d_in[5];
  const float* b2 = (const float*)d_in[6];
  const float* Wp = (const float*)d_in[7];
  const float* bp = (const float*)d_in[8];
  float* out = (float*)d_out;

  // Tier A layout (ush units). H/B2/Bp images ALIAS the A-image region,
  // which is dead after GEMM1 (stream-ordered reuse).
  const size_t NEED_A = 290455560ULL;
  if (ws_size >= NEED_A) {
    ush* ws = (ush*)d_ws;
    ush* A2h = ws;                       // 4096*12544
    ush* A2l = A2h + 51380224;
    ush* B1h = A2l + 51380224;           // 12544*1024
    ush* B1l = B1h + 12845056;
    float* P = (float*)(B1l + 12845056); // 2*4096*1024 f32
    int* mflag = (int*)(P + 8388608);
    // aliased into A2 region (39.3 MB << 205.5 MB):
    ush* H1h = ws;                       // 4096*1024
    ush* H1l = H1h + 4194304;
    ush* H2h = H1l + 4194304;
    ush* H2l = H2h + 4194304;
    ush* B2h = H2l + 4194304;            // 1024*1024
    ush* B2l = B2h + 1048576;
    ush* Bph = B2l + 1048576;            // 384*1024 (zero-padded 324->384)
    ush* Bpl = Bph + 393216;

    mask_probe_kernel<<<1, TB, 0, stream>>>((const uint8_t*)vmask, 4096, mflag);
    conv_A<<<dim3(2, 392, 32), TB, 0, stream>>>(feat, A2h, A2l);
    conv_BT<<<dim3(2, 392, 8), TB, 0, stream>>>(W1, B1h, B1l, 1024, 392);

    gemm_sp<<<dim3(8, 32, 2), TB, 0, stream>>>(A2h, A2l, B1h, B1l, P, 392);
    combine_img<<<dim3(8, 32), TB, 0, stream>>>(P, b1, H1h, H1l);   // A2 dead now

    conv_BT<<<dim3(2, 32, 8), TB, 0, stream>>>(W2, B2h, B2l, 1024, 32);
    conv_BT<<<dim3(2, 32, 3), TB, 0, stream>>>(Wp, Bph, Bpl, 324, 32);

    gemm_sp<<<dim3(8, 32, 2), TB, 0, stream>>>(H1h, H1l, B2h, B2l, P, 32);
    combine_img<<<dim3(8, 32), TB, 0, stream>>>(P, b2, H2h, H2l);
    gemm_sp<<<dim3(3, 32, 2), TB, 0, stream>>>(H2h, H2l, Bph, Bpl, P, 32);
    combine_out<<<dim3(3, 32), TB, 0, stream>>>(P, bp, vmask, mflag, out);
  } else {
    // Tier C fallback: proven round-1 path (needs ~33.6 MB ws)
    float* H1 = (float*)d_ws;
    float* H2 = H1 + (size_t)4096 * 1024;
    int* mflag = (int*)((char*)d_ws + (size_t)2 * 4096 * 1024 * 4);
    mask_probe_kernel<<<1, TB, 0, stream>>>((const uint8_t*)vmask, 4096, mflag);
    mlp_gemm<true,  false, false><<<dim3(8, 32), TB, 0, stream>>>(feat, W1, b1, nullptr, mflag, H1, 1024, 12544);
    mlp_gemm<true,  false, false><<<dim3(8, 32), TB, 0, stream>>>(H1,   W2, b2, nullptr, mflag, H2, 1024, 1024);
    mlp_gemm<false, true,  true ><<<dim3(3, 32), TB, 0, stream>>>(H2,   Wp, bp, vmask,  mflag, out, 324, 1024);
  }
}